// Round 16
// baseline (36.680 us; speedup 1.0000x reference)
//
#include <hip/hip_runtime.h>

#define TREES    256
#define MNODES   1023
#define HD       128
#define VOCAB_SZ 100
#define NCLS     6
#define NTHR     1024

typedef __attribute__((ext_vector_type(8))) short  short8;
typedef __attribute__((ext_vector_type(4))) unsigned short ushort4_t;
typedef __attribute__((ext_vector_type(4))) __bf16 bf16x4;
typedef __attribute__((ext_vector_type(8))) __bf16 bf16x8;
typedef __attribute__((ext_vector_type(4))) float  f32x4;
typedef __attribute__((ext_vector_type(4))) unsigned int uint4_t;

__device__ __forceinline__ unsigned short bfc(float f) {   // native RNE cvt
    return __builtin_bit_cast(unsigned short, (__bf16)f);
}
__device__ __forceinline__ float bf2f(unsigned short s) {
    return __uint_as_float(((unsigned int)s) << 16);
}
__device__ __forceinline__ float fast_tanh(float x) {
    float e = __expf(2.0f * x);
    return 1.0f - 2.0f / (e + 1.0f);
}

// ---- d_ws byte offsets (tables written once by K0) ----
#define WS_ETBL  0         // bf16(E+bh) swizzled, 25600 B
#define WS_GW    25600     // bf16(tanh(E)@Wh) swizzled, 25600 B
#define WS_WHF   51200     // Wh MFMA A-frags, 32768 B
#define WS_ROOTS 84992     // 512 x 128 f32 subtree roots

// ---- K1 LDS (69632 B -> 2 blocks/CU -> 32 waves/CU = 8 waves/SIMD) ----
#define OFF_PING  0        // 16384: agg ping (<=64 rows x 256 B)
#define OFF_GW    16384    // 25600: GW copy -> agg pong (<=32 rows) after L8
#define OFF_ETBL  41984    // 25600: ETBL copy, persistent
#define OFF_NT    67584    // 1023 x u16 (+pad)
#define LDS1      69632

// ================= K0: one-shot table build (8 blocks x 256 thr, r9-proven) ==========
__global__ __launch_bounds__(256)
void k0_prep(const float* __restrict__ E,
             const float* __restrict__ Wh,
             const float* __restrict__ bh,
             unsigned char* __restrict__ wsb)
{
    __shared__ __align__(16) unsigned char tile[4096];
    const int blk = blockIdx.x;
    const int tid = threadIdx.x;

    if (blk == 7) {
        // ETBL = bf16(E + bh), swizzled
        for (int i4 = tid; i4 < VOCAB_SZ * HD / 4; i4 += 256) {
            int row = i4 >> 5, c4 = i4 & 31;
            float4 v  = ((const float4*)E)[i4];
            float4 bv = ((const float4*)bh)[c4];
            ushort4_t e;
            e[0] = bfc(v.x + bv.x); e[1] = bfc(v.y + bv.y);
            e[2] = bfc(v.z + bv.z); e[3] = bfc(v.w + bv.w);
            *(ushort4_t*)(wsb + WS_ETBL + row * 256 + ((c4 * 8) ^ ((row & 7) << 4))) = e;
        }
        // WhFrag: frag-ordered so K1 reads 8 coalesced 16B loads per thread
        for (int fid = tid; fid < 2048; fid += 256) {
            int lane = fid & 63, kt = (fid >> 6) & 3, nt2 = fid >> 8;
            int col = nt2 * 16 + (lane & 15);
            int k0  = kt * 32 + (lane >> 4) * 8;
            short8 sv;
#pragma unroll
            for (int i = 0; i < 8; ++i) sv[i] = (short)bfc(Wh[(k0 + i) * HD + col]);
            *(short8*)(wsb + WS_WHF + fid * 16) = sv;
        }
        return;
    }

    // blocks 0..6: GW rows [blk*16, blk*16+16) = (tanh(E) @ Wh), swapped-operand MFMA
    const int lane = tid & 63;
    const int wv   = tid >> 6;
    const int l16  = lane & 15;
    const int lg   = lane >> 4;
    const int cw   = wv;

    for (int i4 = tid; i4 < 512; i4 += 256) {
        int r = i4 >> 5, c4 = i4 & 31;
        int row = blk * 16 + r;
        if (row < VOCAB_SZ) {
            float4 v = ((const float4*)E)[row * 32 + c4];
            ushort4_t te;
            te[0] = bfc(fast_tanh(v.x)); te[1] = bfc(fast_tanh(v.y));
            te[2] = bfc(fast_tanh(v.z)); te[3] = bfc(fast_tanh(v.w));
            *(ushort4_t*)(tile + r * 256 + ((c4 * 8) ^ ((r & 7) << 4))) = te;
        }
    }
    bf16x8 aT[8];
#pragma unroll
    for (int n2 = 0; n2 < 2; ++n2) {
        const int col = cw * 32 + n2 * 16 + l16;
#pragma unroll
        for (int kt = 0; kt < 4; ++kt) {
            const int k0 = kt * 32 + lg * 8;
            short8 sv;
#pragma unroll
            for (int i = 0; i < 8; ++i) sv[i] = (short)bfc(Wh[(k0 + i) * HD + col]);
            aT[n2 * 4 + kt] = __builtin_bit_cast(bf16x8, sv);
        }
    }
    __syncthreads();

    const int tyr = blk * 16 + l16;
    const int rsw = (l16 & 7) << 4;
    bf16x8 bfrag[4];
#pragma unroll
    for (int kt = 0; kt < 4; ++kt)
        bfrag[kt] = __builtin_bit_cast(bf16x8,
            *(const short8*)(tile + l16 * 256 + ((kt * 64 + lg * 16) ^ rsw)));
    f32x4 acc0 = {0.f, 0.f, 0.f, 0.f};
    f32x4 acc1 = {0.f, 0.f, 0.f, 0.f};
#pragma unroll
    for (int kt = 0; kt < 4; ++kt) {
        acc0 = __builtin_amdgcn_mfma_f32_16x16x32_bf16(aT[kt],     bfrag[kt], acc0, 0, 0, 0);
        acc1 = __builtin_amdgcn_mfma_f32_16x16x32_bf16(aT[4 + kt], bfrag[kt], acc1, 0, 0, 0);
    }
    if (tyr < VOCAB_SZ) {
#pragma unroll
        for (int n2 = 0; n2 < 2; ++n2) {
            const f32x4 a = n2 ? acc1 : acc0;
            const int n0 = cw * 32 + n2 * 16 + lg * 4;
            bf16x4 pk = {(__bf16)a[0], (__bf16)a[1], (__bf16)a[2], (__bf16)a[3]};
            *(bf16x4*)(wsb + WS_GW + tyr * 256 + ((n0 * 2) ^ ((tyr & 7) << 4))) = pk;
        }
    }
}

// ================= K1: half-tree recursion, 1024 thr, 2 blocks/CU ===================
// Swapped-operand level phase (proven): D[n][p] = sum_k Wh[k][n]*agg[p][k].
// MODE 0: h = tanh(EB[ty]+D), fold parent pairs via shfl_xor -> bout.
// MODE 1: subtree root -> global wsout f32 (l16==0 lanes).
template<int P, int MODE>
__device__ __forceinline__ void level_phase(
    unsigned char* lds, const unsigned char* bin, unsigned char* bout,
    const bf16x8 (&aT)[8], const unsigned short* nt, int Loff,
    int cw, int l16, int lg, int g, float* wsout)
{
    constexpr int NBT = (P + 15) / 16;
    for (int bt = g; bt < NBT; bt += 4) {
        const int pb = bt * 16;
        const int p  = pb + l16;
        const int pc = (p < P) ? p : (P - 1);
        const int bswz = (pc & 7) << 4;
        bf16x8 bfrag[4];
#pragma unroll
        for (int kt = 0; kt < 4; ++kt)
            bfrag[kt] = __builtin_bit_cast(bf16x8,
                *(const short8*)(bin + pc * 256 + ((kt * 64 + lg * 16) ^ bswz)));
        f32x4 acc0 = {0.f, 0.f, 0.f, 0.f};
        f32x4 acc1 = {0.f, 0.f, 0.f, 0.f};
#pragma unroll
        for (int kt = 0; kt < 4; ++kt) {
            acc0 = __builtin_amdgcn_mfma_f32_16x16x32_bf16(aT[kt],     bfrag[kt], acc0, 0, 0, 0);
            acc1 = __builtin_amdgcn_mfma_f32_16x16x32_bf16(aT[4 + kt], bfrag[kt], acc1, 0, 0, 0);
        }
        const int ty   = nt[Loff + pc];
        const int tswz = (ty & 7) << 4;
        float h[8];
#pragma unroll
        for (int n2 = 0; n2 < 2; ++n2) {
            const int n0 = cw * 32 + n2 * 16 + lg * 4;
            const uint2 ev = *(const uint2*)(lds + OFF_ETBL + ty * 256 + ((n0 * 2) ^ tswz));
            const f32x4 a = n2 ? acc1 : acc0;
            h[n2*4+0] = fast_tanh(bf2f((unsigned short)(ev.x & 0xffffu)) + a[0]);
            h[n2*4+1] = fast_tanh(bf2f((unsigned short)(ev.x >> 16))     + a[1]);
            h[n2*4+2] = fast_tanh(bf2f((unsigned short)(ev.y & 0xffffu)) + a[2]);
            h[n2*4+3] = fast_tanh(bf2f((unsigned short)(ev.y >> 16))     + a[3]);
        }
        if (MODE == 1) {
            if (l16 == 0) {
#pragma unroll
                for (int n2 = 0; n2 < 2; ++n2) {
                    const int n0 = cw * 32 + n2 * 16 + lg * 4;
                    float4 v = {h[n2*4+0], h[n2*4+1], h[n2*4+2], h[n2*4+3]};
                    *(float4*)(wsout + n0) = v;
                }
            }
        } else {
#pragma unroll
            for (int u = 0; u < 8; ++u) h[u] += __shfl_xor(h[u], 1, 64);
            if ((p < P) && !(l16 & 1)) {
                const int orow = (pb >> 1) + (l16 >> 1);
                const int oswz = (orow & 7) << 4;
#pragma unroll
                for (int n2 = 0; n2 < 2; ++n2) {
                    const int n0 = cw * 32 + n2 * 16 + lg * 4;
                    bf16x4 pk = {(__bf16)h[n2*4+0], (__bf16)h[n2*4+1],
                                 (__bf16)h[n2*4+2], (__bf16)h[n2*4+3]};
                    *(bf16x4*)(bout + orow * 256 + ((n0 * 2) ^ oswz)) = pk;
                }
            }
        }
    }
}

__global__ __launch_bounds__(NTHR, 4)   // cap 128 VGPR; natural use ~52 -> 8 waves/SIMD
void k1_half(const int* __restrict__ node_type,
             const unsigned char* __restrict__ wsb,
             float* __restrict__ roots)
{
    __shared__ __align__(16) unsigned char lds[LDS1];
    unsigned short* nt = (unsigned short*)(lds + OFF_NT);

    const int b    = blockIdx.x;
    const int t    = b >> 1;
    const int s    = b & 1;
    const int tid  = threadIdx.x;
    const int lane = tid & 63;
    const int wv   = tid >> 6;                 // 16 waves = 4 col-waves x 4 groups
    const int l16  = lane & 15;
    const int lg   = lane >> 4;
    const int cw   = wv & 3;
    const int g    = wv >> 2;

    // ---- staging: raw copies only ----
    if (tid < MNODES) nt[tid] = (unsigned short)node_type[t * MNODES + tid];
    for (int i = tid; i < 1600; i += NTHR) {
        *(uint4_t*)(lds + OFF_ETBL + i * 16) = ((const uint4_t*)(wsb + WS_ETBL))[i];
        *(uint4_t*)(lds + OFF_GW   + i * 16) = ((const uint4_t*)(wsb + WS_GW))[i];
    }
    bf16x8 aT[8];                              // 8 coalesced 16B loads
#pragma unroll
    for (int n2 = 0; n2 < 2; ++n2)
#pragma unroll
        for (int kt = 0; kt < 4; ++kt)
            aT[n2 * 4 + kt] = *(const bf16x8*)(wsb + WS_WHF +
                ((((cw * 2 + n2) * 4 + kt) * 64 + lane) << 4));
    __syncthreads();                                          // b1

    // ---- L8 pass (half-tree): 128 depth-8 nodes folded -> agg7 (64 rows, PING) ----
    {
        const int j    = tid >> 4;             // 0..63
        const int c8   = tid & 15;
        const int colb = c8 * 16;
        const int o8   = 255 + s * 128 + 2 * j;
        const int o9   = 511 + s * 256 + 4 * j;
        int tyP0 = nt[o8], tyP1 = nt[o8 + 1];
        int tyAL = nt[o9], tyAR = nt[o9 + 1], tyBL = nt[o9 + 2], tyBR = nt[o9 + 3];
        short8 e0  = *(const short8*)(lds + OFF_ETBL + tyP0 * 256 + (colb ^ ((tyP0 & 7) << 4)));
        short8 e1  = *(const short8*)(lds + OFF_ETBL + tyP1 * 256 + (colb ^ ((tyP1 & 7) << 4)));
        short8 gAL = *(const short8*)(lds + OFF_GW   + tyAL * 256 + (colb ^ ((tyAL & 7) << 4)));
        short8 gAR = *(const short8*)(lds + OFF_GW   + tyAR * 256 + (colb ^ ((tyAR & 7) << 4)));
        short8 gBL = *(const short8*)(lds + OFF_GW   + tyBL * 256 + (colb ^ ((tyBL & 7) << 4)));
        short8 gBR = *(const short8*)(lds + OFF_GW   + tyBR * 256 + (colb ^ ((tyBR & 7) << 4)));
        short8 o;
#pragma unroll
        for (int u = 0; u < 8; ++u) {
            float hA = fast_tanh(bf2f((unsigned short)e0[u]) + bf2f((unsigned short)gAL[u]) +
                                 bf2f((unsigned short)gAR[u]));
            float hB = fast_tanh(bf2f((unsigned short)e1[u]) + bf2f((unsigned short)gBL[u]) +
                                 bf2f((unsigned short)gBR[u]));
            o[u] = (short)bfc(hA + hB);
        }
        *(short8*)(lds + OFF_PING + j * 256 + (colb ^ ((j & 7) << 4))) = o;
    }
    __syncthreads();                                          // b2 (GW dead)

    // ---- subtree levels depth 7..1 ----
    unsigned char* PING = lds + OFF_PING;
    unsigned char* PONG = lds + OFF_GW;
    float* wsout = roots + (t * 2 + s) * HD;
    level_phase<64, 0>(lds, PING, PONG, aT, nt, 127 + s * 64, cw, l16, lg, g, wsout); __syncthreads();
    level_phase<32, 0>(lds, PONG, PING, aT, nt,  63 + s * 32, cw, l16, lg, g, wsout); __syncthreads();
    level_phase<16, 0>(lds, PING, PONG, aT, nt,  31 + s * 16, cw, l16, lg, g, wsout); __syncthreads();
    level_phase< 8, 0>(lds, PONG, PING, aT, nt,  15 + s *  8, cw, l16, lg, g, wsout); __syncthreads();
    level_phase< 4, 0>(lds, PING, PONG, aT, nt,   7 + s *  4, cw, l16, lg, g, wsout); __syncthreads();
    level_phase< 2, 0>(lds, PONG, PING, aT, nt,   3 + s *  2, cw, l16, lg, g, wsout); __syncthreads();
    level_phase< 1, 1>(lds, PING, PONG, aT, nt,   1 + s,      cw, l16, lg, g, wsout);
}

// ================= K2: root update (full f32) + classifier head (r9-proven) ==========
__global__ __launch_bounds__(64)
void k2_root(const int* __restrict__ node_type,
             const float* __restrict__ E,
             const float* __restrict__ Wh,
             const float* __restrict__ bh,
             const float* __restrict__ Wc,
             const float* __restrict__ bc,
             const float* __restrict__ roots,
             float* __restrict__ out)
{
    __shared__ float agg[HD];
    const int t    = blockIdx.x;
    const int lane = threadIdx.x;

    const float* w0 = roots + t * 2 * HD;
    agg[lane]      = w0[lane]      + w0[HD + lane];
    agg[lane + 64] = w0[lane + 64] + w0[HD + lane + 64];
    __syncthreads();

    float x0 = 0.f, x1 = 0.f;
#pragma unroll 8
    for (int k = 0; k < HD; ++k) {
        float a = agg[k];
        x0 += a * Wh[k * HD + lane];
        x1 += a * Wh[k * HD + lane + 64];
    }
    int ty = node_type[t * MNODES];
    float h0 = fast_tanh(E[ty * HD + lane]      + x0 + bh[lane]);
    float h1 = fast_tanh(E[ty * HD + lane + 64] + x1 + bh[lane + 64]);

    float lgt[NCLS];
#pragma unroll
    for (int c = 0; c < NCLS; ++c) {
        float v = h0 * Wc[lane * NCLS + c] + h1 * Wc[(lane + 64) * NCLS + c];
#pragma unroll
        for (int off = 32; off > 0; off >>= 1)
            v += __shfl_xor(v, off, 64);
        lgt[c] = v + bc[c];
    }
    if (lane == 0) {
        float mx = lgt[0];
#pragma unroll
        for (int c = 1; c < NCLS; ++c) mx = fmaxf(mx, lgt[c]);
        float sum = 0.f;
#pragma unroll
        for (int c = 0; c < NCLS; ++c) sum += __expf(lgt[c] - mx);
        float lse = mx + __logf(sum);
#pragma unroll
        for (int c = 0; c < NCLS; ++c) out[t * NCLS + c] = lgt[c] - lse;
    }
}

extern "C" void kernel_launch(void* const* d_in, const int* in_sizes, int n_in,
                              void* d_out, int out_size, void* d_ws, size_t ws_size,
                              hipStream_t stream) {
    const int*   node_type = (const int*)d_in[0];
    // d_in[1]=parent_idx, d_in[2]=depth, d_in[3]=root_idx: static tree structure, unused
    const float* E  = (const float*)d_in[4];
    const float* Wh = (const float*)d_in[5];
    const float* bh = (const float*)d_in[6];
    const float* Wc = (const float*)d_in[7];
    const float* bc = (const float*)d_in[8];
    float* out = (float*)d_out;
    unsigned char* wsb = (unsigned char*)d_ws;
    float* roots = (float*)(wsb + WS_ROOTS);

    k0_prep<<<dim3(8),         dim3(256),  0, stream>>>(E, Wh, bh, wsb);
    k1_half<<<dim3(TREES * 2), dim3(NTHR), 0, stream>>>(node_type, wsb, roots);
    k2_root<<<dim3(TREES),     dim3(64),   0, stream>>>(node_type, E, Wh, bh, Wc, bc, roots, out);
}

// Round 17
// 24.584 us; speedup vs baseline: 1.4920x; 1.4920x over previous
//
#include <hip/hip_runtime.h>

#define TREES    256
#define MNODES   1023
#define HD       128
#define VOCAB_SZ 100
#define NCLS     6
#define NTHR     1024

typedef __attribute__((ext_vector_type(8))) short  short8;
typedef __attribute__((ext_vector_type(4))) unsigned short ushort4_t;
typedef __attribute__((ext_vector_type(4))) __bf16 bf16x4;
typedef __attribute__((ext_vector_type(8))) __bf16 bf16x8;
typedef __attribute__((ext_vector_type(4))) float  f32x4;

__device__ __forceinline__ unsigned short bfc(float f) {   // native RNE cvt
    return __builtin_bit_cast(unsigned short, (__bf16)f);
}
__device__ __forceinline__ float bf2f(unsigned short s) {
    return __uint_as_float(((unsigned int)s) << 16);
}
__device__ __forceinline__ float fast_tanh(float x) {
    float e = __expf(2.0f * x);
    return 1.0f - 2.0f / (e + 1.0f);
}

// Monolithic LDS (118272 B, 1 block/CU) — r15 layout (best: 26.62 us):
//  R1   [0,32768):      tanhE 25600 (dead after GW GEMM) -> agg ping (<=128 rows)
//  GW   [32768,58368):  GW 25600 (dead after L8 pass) -> agg pong (<=64 rows)
//  WHT  [58368,91136):  WhT bf16 swz, PERSISTENT
//  ETBL [91136,116736): bf16(E+bh) swz, persistent
//  NT   [116736,117760): 1023 x u8 ; HROOT [117760,118272): 128 f32
#define OFF_R1    0
#define OFF_GW    32768
#define OFF_WHT   58368
#define OFF_ETBL  91136
#define OFF_NT    116736
#define OFF_HROOT 117760
#define LDS_BYTES 118272

// Swapped-operand level phase (proven): D[n][p] = sum_k Wh[k][n]*agg[p][k];
// lane col = parent p. MODE 0: h = tanh(EB[ty]+D), fold pairs via shfl_xor -> bout.
// MODE 1: root h -> hroot (LDS, f32).
template<int P, int MODE>
__device__ __forceinline__ void level_phase(
    unsigned char* lds, const unsigned char* bin, unsigned char* bout,
    const bf16x8 (&aT)[8], const unsigned char* nt, int Loff,
    int cw, int l16, int lg, int g, float* hroot)
{
    constexpr int NBT = (P + 15) / 16;
    for (int bt = g; bt < NBT; bt += 4) {
        const int pb = bt * 16;
        const int p  = pb + l16;
        const int pc = (p < P) ? p : (P - 1);
        const int bswz = (pc & 7) << 4;
        bf16x8 bfrag[4];
#pragma unroll
        for (int kt = 0; kt < 4; ++kt)
            bfrag[kt] = __builtin_bit_cast(bf16x8,
                *(const short8*)(bin + pc * 256 + ((kt * 64 + lg * 16) ^ bswz)));
        f32x4 acc0 = {0.f, 0.f, 0.f, 0.f};
        f32x4 acc1 = {0.f, 0.f, 0.f, 0.f};
#pragma unroll
        for (int kt = 0; kt < 4; ++kt) {
            acc0 = __builtin_amdgcn_mfma_f32_16x16x32_bf16(aT[kt],     bfrag[kt], acc0, 0, 0, 0);
            acc1 = __builtin_amdgcn_mfma_f32_16x16x32_bf16(aT[4 + kt], bfrag[kt], acc1, 0, 0, 0);
        }
        const int ty   = nt[Loff + pc];
        const int tswz = (ty & 7) << 4;
        float h[8];
#pragma unroll
        for (int n2 = 0; n2 < 2; ++n2) {
            const int n0 = cw * 32 + n2 * 16 + lg * 4;
            const uint2 ev = *(const uint2*)(lds + OFF_ETBL + ty * 256 + ((n0 * 2) ^ tswz));
            const f32x4 a = n2 ? acc1 : acc0;
            h[n2*4+0] = fast_tanh(bf2f((unsigned short)(ev.x & 0xffffu)) + a[0]);
            h[n2*4+1] = fast_tanh(bf2f((unsigned short)(ev.x >> 16))     + a[1]);
            h[n2*4+2] = fast_tanh(bf2f((unsigned short)(ev.y & 0xffffu)) + a[2]);
            h[n2*4+3] = fast_tanh(bf2f((unsigned short)(ev.y >> 16))     + a[3]);
        }
        if (MODE == 1) {
            if (l16 == 0) {
#pragma unroll
                for (int n2 = 0; n2 < 2; ++n2) {
                    const int n0 = cw * 32 + n2 * 16 + lg * 4;
                    float4 v = {h[n2*4+0], h[n2*4+1], h[n2*4+2], h[n2*4+3]};
                    *(float4*)(hroot + n0) = v;
                }
            }
        } else {
#pragma unroll
            for (int u = 0; u < 8; ++u) h[u] += __shfl_xor(h[u], 1, 64);
            if ((p < P) && !(l16 & 1)) {
                const int orow = (pb >> 1) + (l16 >> 1);
                const int oswz = (orow & 7) << 4;
#pragma unroll
                for (int n2 = 0; n2 < 2; ++n2) {
                    const int n0 = cw * 32 + n2 * 16 + lg * 4;
                    bf16x4 pk = {(__bf16)h[n2*4+0], (__bf16)h[n2*4+1],
                                 (__bf16)h[n2*4+2], (__bf16)h[n2*4+3]};
                    *(bf16x4*)(bout + orow * 256 + ((n0 * 2) ^ oswz)) = pk;
                }
            }
        }
    }
}

__global__ __launch_bounds__(NTHR, 4)
void tree_rnn_kernel(const int* __restrict__ node_type,
                     const float* __restrict__ E,
                     const float* __restrict__ Wh,
                     const float* __restrict__ bh,
                     const float* __restrict__ Wc,
                     const float* __restrict__ bc,
                     float* __restrict__ out)
{
    __shared__ __align__(16) unsigned char lds[LDS_BYTES];
    unsigned char* nt    = (unsigned char*)(lds + OFF_NT);
    float*         hroot = (float*)(lds + OFF_HROOT);

    const int t    = blockIdx.x;
    const int tid  = threadIdx.x;
    const int lane = tid & 63;
    const int wv   = tid >> 6;                 // 16 waves = 4 col-waves x 4 groups
    const int l16  = lane & 15;
    const int lg   = lane >> 4;
    const int cw   = wv & 3;                   // owns output cols [cw*32, cw*32+32)
    const int g    = wv >> 2;                  // parent-btile group

    // ---------------- staging (all coalesced global reads) ----------------
    if (tid < MNODES) nt[tid] = (unsigned char)node_type[t * MNODES + tid];
    for (int i4 = tid; i4 < VOCAB_SZ * HD / 4; i4 += NTHR) {
        int row = i4 >> 5, c4 = i4 & 31;
        float4 v  = ((const float4*)E)[i4];
        float4 bv = ((const float4*)bh)[c4];
        ushort4_t e, te;
        e[0] = bfc(v.x + bv.x); e[1] = bfc(v.y + bv.y);
        e[2] = bfc(v.z + bv.z); e[3] = bfc(v.w + bv.w);
        te[0] = bfc(fast_tanh(v.x)); te[1] = bfc(fast_tanh(v.y));
        te[2] = bfc(fast_tanh(v.z)); te[3] = bfc(fast_tanh(v.w));
        int boff = row * 256 + ((c4 * 8) ^ ((row & 7) << 4));
        *(ushort4_t*)(lds + OFF_ETBL + boff) = e;
        *(ushort4_t*)(lds + OFF_R1   + boff) = te;
    }
    // Wh [k][n] f32 -> WhT [n][k] bf16 swz (persistent): lane holds 4 K-consecutive
    // values for fixed column n (4 coalesced loads), writes ONE 8B bf16x4.
    // Layout identity with aT reads: writes at (k0*2)^swz and (k0*2+8)^swz tile the
    // 16B read granule ((kt*64+lg*16)^swz) exactly (swz only touches bits 4..6).
    {
        const int n  = tid & 127;              // column
        const int kb = tid >> 7;               // k-group 0..7 per pass
        const int nswz = (n & 7) << 4;
#pragma unroll
        for (int it = 0; it < 4; ++it) {
            const int k0 = (it * 8 + kb) * 4;  // 4-aligned k
            bf16x4 w = {(__bf16)Wh[(k0 + 0) * HD + n], (__bf16)Wh[(k0 + 1) * HD + n],
                        (__bf16)Wh[(k0 + 2) * HD + n], (__bf16)Wh[(k0 + 3) * HD + n]};
            *(bf16x4*)(lds + OFF_WHT + n * 256 + ((k0 * 2) ^ nswz)) = w;
        }
    }
    __syncthreads();                                          // b1: stage done

    // ---- MERGED PHASE: aT frags from persistent WhT + GW GEMM ----
    bf16x8 aT[8];
#pragma unroll
    for (int n2 = 0; n2 < 2; ++n2) {
        const int ncol = cw * 32 + n2 * 16 + l16;
        const int nswz = (ncol & 7) << 4;
#pragma unroll
        for (int kt = 0; kt < 4; ++kt)
            aT[n2 * 4 + kt] = __builtin_bit_cast(bf16x8,
                *(const short8*)(lds + OFF_WHT + ncol * 256 + ((kt * 64 + lg * 16) ^ nswz)));
    }
    for (int bt = g; bt < 7; bt += 4) {        // GW[ty][n] = (tanh(E) @ Wh)[ty][n]
        const int tyr = bt * 16 + l16;
        const int tyc = (tyr < VOCAB_SZ) ? tyr : (VOCAB_SZ - 1);
        const int bswz = (tyc & 7) << 4;
        bf16x8 bfrag[4];
#pragma unroll
        for (int kt = 0; kt < 4; ++kt)
            bfrag[kt] = __builtin_bit_cast(bf16x8,
                *(const short8*)(lds + OFF_R1 + tyc * 256 + ((kt * 64 + lg * 16) ^ bswz)));
        f32x4 acc0 = {0.f, 0.f, 0.f, 0.f};
        f32x4 acc1 = {0.f, 0.f, 0.f, 0.f};
#pragma unroll
        for (int kt = 0; kt < 4; ++kt) {
            acc0 = __builtin_amdgcn_mfma_f32_16x16x32_bf16(aT[kt],     bfrag[kt], acc0, 0, 0, 0);
            acc1 = __builtin_amdgcn_mfma_f32_16x16x32_bf16(aT[4 + kt], bfrag[kt], acc1, 0, 0, 0);
        }
        if (tyr < VOCAB_SZ) {
            const int tswz = (tyr & 7) << 4;
#pragma unroll
            for (int n2 = 0; n2 < 2; ++n2) {
                const f32x4 a = n2 ? acc1 : acc0;
                const int n0 = cw * 32 + n2 * 16 + lg * 4;
                bf16x4 pk = {(__bf16)a[0], (__bf16)a[1], (__bf16)a[2], (__bf16)a[3]};
                *(bf16x4*)(lds + OFF_GW + tyr * 256 + ((n0 * 2) ^ tswz)) = pk;
            }
        }
    }
    __syncthreads();                                          // b2: GW ready

    // ---- L8 pass: h8 = tanh(ETBL[ty8]+GW[tyL]+GW[tyR]), fold pairs -> agg7 (128 rows, R1) ----
#pragma unroll
    for (int it = 0; it < 2; ++it) {
        const int idx = it * NTHR + tid;       // 128 parents x 16 chunks
        const int j   = idx >> 4;
        const int c8  = idx & 15;
        const int colb = c8 * 16;
        const int o8  = 255 + 2 * j;
        const int o9  = 511 + 4 * j;
        int tyP0 = nt[o8], tyP1 = nt[o8 + 1];
        int tyAL = nt[o9], tyAR = nt[o9 + 1], tyBL = nt[o9 + 2], tyBR = nt[o9 + 3];
        short8 e0  = *(const short8*)(lds + OFF_ETBL + tyP0 * 256 + (colb ^ ((tyP0 & 7) << 4)));
        short8 e1  = *(const short8*)(lds + OFF_ETBL + tyP1 * 256 + (colb ^ ((tyP1 & 7) << 4)));
        short8 gAL = *(const short8*)(lds + OFF_GW   + tyAL * 256 + (colb ^ ((tyAL & 7) << 4)));
        short8 gAR = *(const short8*)(lds + OFF_GW   + tyAR * 256 + (colb ^ ((tyAR & 7) << 4)));
        short8 gBL = *(const short8*)(lds + OFF_GW   + tyBL * 256 + (colb ^ ((tyBL & 7) << 4)));
        short8 gBR = *(const short8*)(lds + OFF_GW   + tyBR * 256 + (colb ^ ((tyBR & 7) << 4)));
        short8 o;
#pragma unroll
        for (int u = 0; u < 8; ++u) {
            float hA = fast_tanh(bf2f((unsigned short)e0[u]) + bf2f((unsigned short)gAL[u]) +
                                 bf2f((unsigned short)gAR[u]));
            float hB = fast_tanh(bf2f((unsigned short)e1[u]) + bf2f((unsigned short)gBL[u]) +
                                 bf2f((unsigned short)gBR[u]));
            o[u] = (short)bfc(hA + hB);
        }
        *(short8*)(lds + OFF_R1 + j * 256 + (colb ^ ((j & 7) << 4))) = o;
    }
    __syncthreads();                                          // b3: agg7 ready (GW dead)

    // ---------------- levels 7..0, ping-pong R1 <-> GW region ----------------
    unsigned char* R1   = lds + OFF_R1;
    unsigned char* PONG = lds + OFF_GW;
    level_phase<128, 0>(lds, R1,   PONG, aT, nt, 127, cw, l16, lg, g, hroot); __syncthreads();
    level_phase< 64, 0>(lds, PONG, R1,   aT, nt,  63, cw, l16, lg, g, hroot); __syncthreads();
    level_phase< 32, 0>(lds, R1,   PONG, aT, nt,  31, cw, l16, lg, g, hroot); __syncthreads();
    level_phase< 16, 0>(lds, PONG, R1,   aT, nt,  15, cw, l16, lg, g, hroot); __syncthreads();
    level_phase<  8, 0>(lds, R1,   PONG, aT, nt,   7, cw, l16, lg, g, hroot); __syncthreads();
    level_phase<  4, 0>(lds, PONG, R1,   aT, nt,   3, cw, l16, lg, g, hroot); __syncthreads();
    level_phase<  2, 0>(lds, R1,   PONG, aT, nt,   1, cw, l16, lg, g, hroot); __syncthreads();
    level_phase<  1, 1>(lds, PONG, R1,   aT, nt,   0, cw, l16, lg, g, hroot); __syncthreads();

    // ---------------- classifier head + log_softmax (wave 0) ----------------
    if (tid < 64) {
        float hA = hroot[tid];
        float hB = hroot[tid + 64];
        float lgt[NCLS];
#pragma unroll
        for (int c = 0; c < NCLS; ++c) {
            float v = hA * Wc[tid * NCLS + c] + hB * Wc[(tid + 64) * NCLS + c];
#pragma unroll
            for (int off = 32; off > 0; off >>= 1)
                v += __shfl_xor(v, off, 64);
            lgt[c] = v + bc[c];
        }
        if (tid == 0) {
            float mx = lgt[0];
#pragma unroll
            for (int c = 1; c < NCLS; ++c) mx = fmaxf(mx, lgt[c]);
            float s = 0.f;
#pragma unroll
            for (int c = 0; c < NCLS; ++c) s += __expf(lgt[c] - mx);
            float lse = mx + __logf(s);
#pragma unroll
            for (int c = 0; c < NCLS; ++c) out[t * NCLS + c] = lgt[c] - lse;
        }
    }
}

extern "C" void kernel_launch(void* const* d_in, const int* in_sizes, int n_in,
                              void* d_out, int out_size, void* d_ws, size_t ws_size,
                              hipStream_t stream) {
    const int*   node_type = (const int*)d_in[0];
    // d_in[1]=parent_idx, d_in[2]=depth, d_in[3]=root_idx: static tree structure, unused
    const float* E  = (const float*)d_in[4];
    const float* Wh = (const float*)d_in[5];
    const float* bh = (const float*)d_in[6];
    const float* Wc = (const float*)d_in[7];
    const float* bc = (const float*)d_in[8];
    float* out = (float*)d_out;
    tree_rnn_kernel<<<dim3(TREES), dim3(NTHR), 0, stream>>>(node_type, E, Wh, bh, Wc, bc, out);
}